// Round 15
// baseline (75.200 us; speedup 1.0000x reference)
//
#include <hip/hip_runtime.h>
#include <math.h>

#define C_CH 256
#define PRE 14
#define NPOOL 7
#define PIX (NPOOL * NPOOL)            // 49
#define OUT_PER_ROI (C_CH * PIX)       // 12544
#define HALF_OUT (128 * PIX)           // 6272
#define SROW 132                       // sout row stride: 128 ch + 4 pad (pixel-major)

// level offsets in bf16 elements inside HWC workspace
#define OFF_P2 0
#define OFF_P3 16777216u
#define OFF_P4 20971520u
#define OFF_P5 22020096u
#define WS_ELEMS 22282240u             // bf16 elements; perm array lives after this

#define RB 528                         // transpose LDS row stride in bytes (512 + 16)
#define NTRANS 680                     // transpose blocks (1..NTRANS); block 0 = sorter
#define NBKT 4096                      // sort buckets: lvl(2b) x yband(5b) x xband(5b)

static __device__ __forceinline__ unsigned short f2bf(float f) {
    unsigned int u = __float_as_uint(f);
    unsigned int r = (u + 0x7FFFu + ((u >> 16) & 1u)) >> 16;   // RNE
    return (unsigned short)r;
}
static __device__ __forceinline__ float bfLO(unsigned int u) { return __uint_as_float(u << 16); }
static __device__ __forceinline__ float bfHI(unsigned int u) { return __uint_as_float(u & 0xFFFF0000u); }

static __device__ __forceinline__ float4 bf4(uint2 u) {
    return make_float4(bfLO(u.x), bfHI(u.x), bfLO(u.y), bfHI(u.y));
}
static __device__ __forceinline__ float4 fma4(float4 a, float s, float4 c) {
    return make_float4(fmaf(a.x, s, c.x), fmaf(a.y, s, c.y), fmaf(a.z, s, c.z), fmaf(a.w, s, c.w));
}
static __device__ __forceinline__ float4 mul4(float4 a, float s) {
    return make_float4(a.x * s, a.y * s, a.z * s, a.w * s);
}
static __device__ __forceinline__ float4 max4(float4 a, float4 b) {
    return make_float4(fmaxf(a.x, b.x), fmaxf(a.y, b.y), fmaxf(a.z, b.z), fmaxf(a.w, b.w));
}

// ---------------- fused transpose CHW fp32 -> HWC bf16 + ROI fine bucket sort ----------------
__global__ __launch_bounds__(256) void transpose_all_k(
    const float* __restrict__ p2, const float* __restrict__ p3,
    const float* __restrict__ p4, const float* __restrict__ p5,
    unsigned short* __restrict__ ws, const float* __restrict__ rois,
    unsigned* __restrict__ perm, int N) {
    __shared__ unsigned char lds[128 * RB];    // 67584 B

    if (blockIdx.x == 0) {
        int* hist = (int*)lds;                                   // 16384 B
        int* tsum = (int*)(lds + NBKT * 4);                      // 1024 B
        unsigned short* kbuf = (unsigned short*)(lds + NBKT * 4 + 1024);  // 2048 B
        const int t = threadIdx.x;
        #pragma unroll
        for (int k = 0; k < NBKT / 256; ++k) hist[t + (k << 8)] = 0;
        __syncthreads();
        for (int i = t; i < N; i += 256) {
            const float x1 = rois[i * 5 + 1];
            const float y1 = rois[i * 5 + 2];
            const float x2 = rois[i * 5 + 3];
            const float y2 = rois[i * 5 + 4];
            float w = x2 - x1; w = (w <= 0.f) ? 1e-14f : w;
            float h = y2 - y1; h = (h <= 0.f) ? 1e-14f : h;
            float kf = 4.f + log2f(sqrtf(w * h) * (1.f / 224.f));
            kf = fminf(fmaxf(kf, 2.f), 5.f);
            const float kr = rintf(kf);
            const int lvl = (int)kr - 2;                 // 0..3
            const float inv = exp2f(-kr);
            const int yi = (int)(y1 * inv);
            const int xi = (int)(x1 * inv);
            const int sh = 3 - lvl;                      // 32 bands per level
            const int yb = (yi >> sh) & 31;
            const int xb = (xi >> sh) & 31;
            const int bkt = (lvl << 10) | (yb << 5) | xb;
            kbuf[i] = (unsigned short)bkt;
            atomicAdd(&hist[bkt], 1);
        }
        __syncthreads();
        {
            const int b0 = t << 4;
            int s = 0;
            #pragma unroll
            for (int k = 0; k < 16; ++k) s += hist[b0 + k];
            tsum[t] = s;
        }
        __syncthreads();
        if (t == 0) {
            int acc = 0;
            for (int k = 0; k < 256; ++k) { const int v = tsum[k]; tsum[k] = acc; acc += v; }
        }
        __syncthreads();
        {
            const int b0 = t << 4;
            int run = tsum[t];
            #pragma unroll
            for (int k = 0; k < 16; ++k) { const int v = hist[b0 + k]; hist[b0 + k] = run; run += v; }
        }
        __syncthreads();
        for (int i = t; i < N; i += 256) {
            const int pos = atomicAdd(&hist[kbuf[i]], 1);
            perm[pos] = (unsigned)i;
        }
        return;
    }

    int b = blockIdx.x - 1;
    const float* __restrict__ src;
    int HW2; unsigned int off;
    if (b < 512)      { src = p2; HW2 = 65536; off = OFF_P2; }
    else if (b < 640) { src = p3; HW2 = 16384; off = OFF_P3; b -= 512; }
    else if (b < 672) { src = p4; HW2 = 4096;  off = OFF_P4; b -= 640; }
    else              { src = p5; HW2 = 1024;  off = OFF_P5; b -= 672; }
    const int hw0 = b << 7;

    const int t   = threadIdx.x;
    const int hwq = t & 31;
    const int cg  = t >> 5;
    const int key = (hwq & 7) << 4;

    #pragma unroll
    for (int s = 0; s < 8; ++s) {
        const int c0 = (cg << 2) + (s << 5);
        const float* g = src + (size_t)c0 * HW2 + hw0 + (hwq << 2);
        const float4 a0 = *(const float4*)(g);
        const float4 a1 = *(const float4*)(g + HW2);
        const float4 a2 = *(const float4*)(g + 2 * (size_t)HW2);
        const float4 a3 = *(const float4*)(g + 3 * (size_t)HW2);
        const int cb = (c0 << 1) ^ key;
        unsigned char* base = &lds[(hwq << 2) * RB + cb];
        ushort4 w;
        w.x = f2bf(a0.x); w.y = f2bf(a1.x); w.z = f2bf(a2.x); w.w = f2bf(a3.x);
        *(ushort4*)(base) = w;
        w.x = f2bf(a0.y); w.y = f2bf(a1.y); w.z = f2bf(a2.y); w.w = f2bf(a3.y);
        *(ushort4*)(base + RB) = w;
        w.x = f2bf(a0.z); w.y = f2bf(a1.z); w.z = f2bf(a2.z); w.w = f2bf(a3.z);
        *(ushort4*)(base + 2 * RB) = w;
        w.x = f2bf(a0.w); w.y = f2bf(a1.w); w.z = f2bf(a2.w); w.w = f2bf(a3.w);
        *(ushort4*)(base + 3 * RB) = w;
    }
    __syncthreads();

    char* __restrict__ dstb = (char*)(ws + off + ((size_t)hw0 << 8));
    const int chunk = t & 31;
    const int hwl   = t >> 5;
    #pragma unroll
    for (int p = 0; p < 16; ++p) {
        const int hw = (p << 3) + hwl;
        const int k2 = ((hw >> 2) & 7) << 4;
        const uint4 v = *(const uint4*)&lds[hw * RB + ((chunk << 4) ^ k2)];
        *(uint4*)(dstb + hw * 512 + (chunk << 4)) = v;
    }
}

// ---------------- main ROI-align + 2x2 maxpool (128 channels per block) ----------------
// Register-carried corner reuse: thread (4-ch group, pool row) sweeps sample columns
// left-to-right caching the last two texel columns (4 y-rows, y-deduped) in registers.
// All reuse decisions are block-uniform (scalar branches). Cuts line touches ~2.5x.
template <bool HWC>
__global__ __launch_bounds__(256, 4) void roi_align_k(
    const float* __restrict__ p2, const float* __restrict__ p3,
    const float* __restrict__ p4, const float* __restrict__ p5,
    const unsigned short* __restrict__ ws, const float* __restrict__ rois,
    const unsigned* __restrict__ perm, int N, float* __restrict__ out) {

    __shared__ float sxw0[PRE], sxw1[PRE], syw0[PRE], syw1[PRE];
    __shared__ int   sxc0[PRE], sxc1[PRE], syc0[PRE], syc1[PRE];
    __shared__ float sout[PIX * SROW];          // 25872 B (pixel-major)

    int n;
    if (HWC) {
        const int bid = blockIdx.x;
        int spos;
        if ((N & 7) == 0) spos = (bid & 7) * (N >> 3) + (bid >> 3);   // XCD-chunked
        else              spos = bid;
        n = (int)perm[spos];
    } else {
        n = blockIdx.x;
    }
    const int ch0 = blockIdx.y << 7;            // 0 or 128
    const float x1 = rois[n * 5 + 1];
    const float y1 = rois[n * 5 + 2];
    const float x2 = rois[n * 5 + 3];
    const float y2 = rois[n * 5 + 4];

    float w = x2 - x1; w = (w <= 0.f) ? 1e-14f : w;
    float h = y2 - y1; h = (h <= 0.f) ? 1e-14f : h;
    float kf = 4.f + log2f(sqrtf(w * h) * (1.f / 224.f));
    kf = fminf(fmaxf(kf, 2.f), 5.f);
    const float kr = rintf(kf);                 // round-half-even == jnp.round
    const int   lvl = (int)kr - 2;              // 0..3
    const float scale = exp2f(kr);
    const int   HW = 256 >> lvl;

    const int t = threadIdx.x;

    if (t < 2 * PRE) {
        const bool isx = t < PRE;
        const int  j = isx ? t : t - PRE;
        const float a1 = isx ? x1 : y1;
        const float a2 = isx ? x2 : y2;
        const float a1s = a1 / scale, a2s = a2 / scale;
        const float cen  = (a1s + a2s) * 0.5f;
        const float half = (a2s - a1s) * 0.5f;
        const float tt = -1.f + (2.f / 13.f) * (float)j;
        const float p  = cen + tt * half;
        const float p0 = floorf(p);
        const float d  = p - p0;
        const float HWf = (float)HW;
        const float m0 = (p0 >= 0.f && p0 < HWf) ? 1.f : 0.f;
        const float m1 = (p0 + 1.f >= 0.f && p0 + 1.f < HWf) ? 1.f : 0.f;
        const int c0i = min(max((int)p0, 0), HW - 1);
        const int c1i = min(max((int)p0 + 1, 0), HW - 1);
        if (isx) { sxw0[j] = (1.f - d) * m0; sxw1[j] = d * m1; sxc0[j] = c0i; sxc1[j] = c1i; }
        else     { syw0[j] = (1.f - d) * m0; syw1[j] = d * m1; syc0[j] = c0i; syc1[j] = c1i; }
    }
    __syncthreads();

    const int g    = t & 31;                    // 32 groups x 4 ch = 128 ch
    const int slot = t >> 5;                    // 0..7; rows 0..6 active

    if (HWC) {
        const unsigned int off = (lvl == 0) ? OFF_P2 : (lvl == 1) ? OFF_P3 : (lvl == 2) ? OFF_P4 : OFF_P5;
        const char* __restrict__ base = (const char*)(ws + off) + ((ch0 + (g << 2)) << 1);

        if (slot < NPOOL) {
            const int oy = slot;
            const int i0 = oy << 1, i1 = i0 + 1;
            const int R0 = syc0[i0], R1 = syc1[i0], R2 = syc0[i1], R3 = syc1[i1];
            const float wy0 = syw0[i0], wy1 = syw1[i0], wy2 = syw0[i1], wy3 = syw1[i1];
            const int rb0 = (R0 * HW) << 9;
            const int rb1 = (R1 * HW) << 9;
            const int rb2 = (R2 * HW) << 9;
            const int rb3 = (R3 * HW) << 9;

            int xA = -1, xB = -1;
            uint2 A0, A1, A2, A3, B0, B1, B2, B3;
            float4 pprev = make_float4(0.f, 0.f, 0.f, 0.f);

            #pragma unroll 1
            for (int j = 0; j < PRE; ++j) {
                const int a = sxc0[j], b = sxc1[j];
                const float wxa = sxw0[j], wxb = sxw1[j];
                uint2 Ca0, Ca1, Ca2, Ca3, Cb0, Cb1, Cb2, Cb3;

                // ---- column a (reuse checks are block-uniform -> scalar branches) ----
                if (a == xA)      { Ca0 = A0; Ca1 = A1; Ca2 = A2; Ca3 = A3; }
                else if (a == xB) { Ca0 = B0; Ca1 = B1; Ca2 = B2; Ca3 = B3; }
                else {
                    const int xo = a << 9;
                    Ca0 = *(const uint2*)(base + (rb0 + xo));
                    if (R1 == R0) Ca1 = Ca0; else Ca1 = *(const uint2*)(base + (rb1 + xo));
                    if (R2 == R1) Ca2 = Ca1; else if (R2 == R0) Ca2 = Ca0;
                    else Ca2 = *(const uint2*)(base + (rb2 + xo));
                    if (R3 == R2) Ca3 = Ca2; else Ca3 = *(const uint2*)(base + (rb3 + xo));
                }
                // ---- column b ----
                if (b == a)       { Cb0 = Ca0; Cb1 = Ca1; Cb2 = Ca2; Cb3 = Ca3; }
                else if (b == xB) { Cb0 = B0; Cb1 = B1; Cb2 = B2; Cb3 = B3; }
                else if (b == xA) { Cb0 = A0; Cb1 = A1; Cb2 = A2; Cb3 = A3; }
                else {
                    const int xo = b << 9;
                    Cb0 = *(const uint2*)(base + (rb0 + xo));
                    if (R1 == R0) Cb1 = Cb0; else Cb1 = *(const uint2*)(base + (rb1 + xo));
                    if (R2 == R1) Cb2 = Cb1; else if (R2 == R0) Cb2 = Cb0;
                    else Cb2 = *(const uint2*)(base + (rb2 + xo));
                    if (R3 == R2) Cb3 = Cb2; else Cb3 = *(const uint2*)(base + (rb3 + xo));
                }
                // update cache
                xA = a; A0 = Ca0; A1 = Ca1; A2 = Ca2; A3 = Ca3;
                xB = b; B0 = Cb0; B1 = Cb1; B2 = Cb2; B3 = Cb3;

                // ---- bilinear for samples (i0,j) and (i1,j), 4 channels ----
                // v0 = wxa*(wy0*Ca0 + wy1*Ca1) + wxb*(wy0*Cb0 + wy1*Cb1)
                float4 ta = fma4(bf4(Ca1), wy1, mul4(bf4(Ca0), wy0));
                float4 tb = fma4(bf4(Cb1), wy1, mul4(bf4(Cb0), wy0));
                const float4 v0 = fma4(tb, wxb, mul4(ta, wxa));
                ta = fma4(bf4(Ca3), wy3, mul4(bf4(Ca2), wy2));
                tb = fma4(bf4(Cb3), wy3, mul4(bf4(Cb2), wy2));
                const float4 v1 = fma4(tb, wxb, mul4(ta, wxa));
                const float4 vj = max4(v0, v1);

                if ((j & 1) == 0) {
                    pprev = vj;
                } else {
                    const float4 o = max4(pprev, vj);
                    *(float4*)&sout[(oy * 7 + (j >> 1)) * SROW + (g << 2)] = o;
                }
            }
        }
    } else {
        const int cbase = ch0 + (g << 2);
        const float* __restrict__ fbF = (lvl == 0) ? p2 : (lvl == 1) ? p3 : (lvl == 2) ? p4 : p5;
        const int HW2 = HW * HW;
        for (int p = slot; p < PIX; p += 8) {
            const int oy = p / 7;
            const int ox = p - oy * 7;
            float4 m = make_float4(-3.4e38f, -3.4e38f, -3.4e38f, -3.4e38f);
            #pragma unroll
            for (int sy = 0; sy < 2; ++sy) {
                const int i = oy * 2 + sy;
                const float wy0 = syw0[i], wy1 = syw1[i];
                const int   yc0 = syc0[i], yc1 = syc1[i];
                #pragma unroll
                for (int sx = 0; sx < 2; ++sx) {
                    const int j = ox * 2 + sx;
                    const float w00 = wy0 * sxw0[j], w01 = wy0 * sxw1[j];
                    const float w10 = wy1 * sxw0[j], w11 = wy1 * sxw1[j];
                    const int   xc0 = sxc0[j], xc1 = sxc1[j];
                    float vv[4];
                    #pragma unroll
                    for (int k = 0; k < 4; ++k) {
                        const size_t cb = (size_t)(cbase + k) * HW2;
                        const float a00 = fbF[cb + yc0 * HW + xc0];
                        const float a01 = fbF[cb + yc0 * HW + xc1];
                        const float a10 = fbF[cb + yc1 * HW + xc0];
                        const float a11 = fbF[cb + yc1 * HW + xc1];
                        vv[k] = fmaf(a00, w00, fmaf(a01, w01, fmaf(a10, w10, a11 * w11)));
                    }
                    m.x = fmaxf(m.x, vv[0]);
                    m.y = fmaxf(m.y, vv[1]);
                    m.z = fmaxf(m.z, vv[2]);
                    m.w = fmaxf(m.w, vv[3]);
                }
            }
            *(float4*)&sout[p * SROW + (g << 2)] = m;
        }
    }
    __syncthreads();

    // coalesced NCHW write of this channel-half
    const size_t ob = (size_t)n * OUT_PER_ROI + (size_t)ch0 * PIX;
    for (int o = t; o < HALF_OUT; o += 256) {
        const int c  = o / PIX;
        const int pp = o - c * PIX;
        out[ob + o] = sout[pp * SROW + c];
    }
}

extern "C" void kernel_launch(void* const* d_in, const int* in_sizes, int n_in,
                              void* d_out, int out_size, void* d_ws, size_t ws_size,
                              hipStream_t stream) {
    const float* p2   = (const float*)d_in[0];
    const float* p3   = (const float*)d_in[1];
    const float* p4   = (const float*)d_in[2];
    const float* p5   = (const float*)d_in[3];
    const float* rois = (const float*)d_in[4];
    float* out = (float*)d_out;
    const int N = in_sizes[4] / 5;

    const size_t need = (size_t)WS_ELEMS * sizeof(unsigned short) + 4096;
    if (ws_size >= need && N <= 1024) {
        unsigned short* ws = (unsigned short*)d_ws;
        unsigned* perm = (unsigned*)((char*)d_ws + (size_t)WS_ELEMS * sizeof(unsigned short));
        transpose_all_k<<<NTRANS + 1, 256, 0, stream>>>(p2, p3, p4, p5, ws, rois, perm, N);
        roi_align_k<true><<<dim3(N, 2), 256, 0, stream>>>(p2, p3, p4, p5, ws, rois, perm, N, out);
    } else {
        roi_align_k<false><<<dim3(N, 2), 256, 0, stream>>>(p2, p3, p4, p5, nullptr, rois, nullptr, N, out);
    }
}

// Round 16
// 66.291 us; speedup vs baseline: 1.1344x; 1.1344x over previous
//
#include <hip/hip_runtime.h>
#include <math.h>

#define C_CH 256
#define PRE 14
#define NPOOL 7
#define PIX (NPOOL * NPOOL)            // 49
#define OUT_PER_ROI (C_CH * PIX)       // 12544
#define QTR_OUT (64 * PIX)             // 3136
#define SROW 68                        // sout row stride: 64 ch + 4 pad (pixel-major)
#define WTEX 352                       // max staged window texels (arena 45056 B)

// level offsets in bf16 elements inside HWC workspace
#define OFF_P2 0
#define OFF_P3 16777216u
#define OFF_P4 20971520u
#define OFF_P5 22020096u
#define WS_ELEMS 22282240u             // bf16 elements; perm array lives after this

#define RB 528                         // transpose LDS row stride in bytes (512 + 16)
#define NTRANS 680                     // transpose blocks (1..NTRANS); block 0 = sorter
#define NBKT 4096                      // sort buckets: lvl(2b) x yband(5b) x xband(5b)

static __device__ __forceinline__ unsigned short f2bf(float f) {
    unsigned int u = __float_as_uint(f);
    unsigned int r = (u + 0x7FFFu + ((u >> 16) & 1u)) >> 16;   // RNE
    return (unsigned short)r;
}
static __device__ __forceinline__ float bfLO(unsigned int u) { return __uint_as_float(u << 16); }
static __device__ __forceinline__ float bfHI(unsigned int u) { return __uint_as_float(u & 0xFFFF0000u); }

// 4-channel bilinear from 4 corner uint2 (4 bf16 ch each) and corner weights w
static __device__ __forceinline__ float4 bilerp4(uint2 a00, uint2 a01, uint2 a10, uint2 a11, float4 w) {
    float4 r;
    r.x = fmaf(bfLO(a00.x), w.x, fmaf(bfLO(a01.x), w.y, fmaf(bfLO(a10.x), w.z, bfLO(a11.x) * w.w)));
    r.y = fmaf(bfHI(a00.x), w.x, fmaf(bfHI(a01.x), w.y, fmaf(bfHI(a10.x), w.z, bfHI(a11.x) * w.w)));
    r.z = fmaf(bfLO(a00.y), w.x, fmaf(bfLO(a01.y), w.y, fmaf(bfLO(a10.y), w.z, bfLO(a11.y) * w.w)));
    r.w = fmaf(bfHI(a00.y), w.x, fmaf(bfHI(a01.y), w.y, fmaf(bfHI(a10.y), w.z, bfHI(a11.y) * w.w)));
    return r;
}

// ---------------- fused transpose CHW fp32 -> HWC bf16 + ROI fine bucket sort ----------------
__global__ __launch_bounds__(256) void transpose_all_k(
    const float* __restrict__ p2, const float* __restrict__ p3,
    const float* __restrict__ p4, const float* __restrict__ p5,
    unsigned short* __restrict__ ws, const float* __restrict__ rois,
    unsigned* __restrict__ perm, int N) {
    __shared__ unsigned char lds[128 * RB];    // 67584 B

    if (blockIdx.x == 0) {
        int* hist = (int*)lds;                                   // 16384 B
        int* tsum = (int*)(lds + NBKT * 4);                      // 1024 B
        unsigned short* kbuf = (unsigned short*)(lds + NBKT * 4 + 1024);  // 2048 B
        const int t = threadIdx.x;
        #pragma unroll
        for (int k = 0; k < NBKT / 256; ++k) hist[t + (k << 8)] = 0;
        __syncthreads();
        for (int i = t; i < N; i += 256) {
            const float x1 = rois[i * 5 + 1];
            const float y1 = rois[i * 5 + 2];
            const float x2 = rois[i * 5 + 3];
            const float y2 = rois[i * 5 + 4];
            float w = x2 - x1; w = (w <= 0.f) ? 1e-14f : w;
            float h = y2 - y1; h = (h <= 0.f) ? 1e-14f : h;
            float kf = 4.f + log2f(sqrtf(w * h) * (1.f / 224.f));
            kf = fminf(fmaxf(kf, 2.f), 5.f);
            const float kr = rintf(kf);
            const int lvl = (int)kr - 2;                 // 0..3
            const float inv = exp2f(-kr);
            const int yi = (int)(y1 * inv);
            const int xi = (int)(x1 * inv);
            const int sh = 3 - lvl;                      // 32 bands per level
            const int yb = (yi >> sh) & 31;
            const int xb = (xi >> sh) & 31;
            const int bkt = (lvl << 10) | (yb << 5) | xb;
            kbuf[i] = (unsigned short)bkt;
            atomicAdd(&hist[bkt], 1);
        }
        __syncthreads();
        {
            const int b0 = t << 4;
            int s = 0;
            #pragma unroll
            for (int k = 0; k < 16; ++k) s += hist[b0 + k];
            tsum[t] = s;
        }
        __syncthreads();
        if (t == 0) {
            int acc = 0;
            for (int k = 0; k < 256; ++k) { const int v = tsum[k]; tsum[k] = acc; acc += v; }
        }
        __syncthreads();
        {
            const int b0 = t << 4;
            int run = tsum[t];
            #pragma unroll
            for (int k = 0; k < 16; ++k) { const int v = hist[b0 + k]; hist[b0 + k] = run; run += v; }
        }
        __syncthreads();
        for (int i = t; i < N; i += 256) {
            const int pos = atomicAdd(&hist[kbuf[i]], 1);
            perm[pos] = (unsigned)i;
        }
        return;
    }

    int b = blockIdx.x - 1;
    const float* __restrict__ src;
    int HW2; unsigned int off;
    if (b < 512)      { src = p2; HW2 = 65536; off = OFF_P2; }
    else if (b < 640) { src = p3; HW2 = 16384; off = OFF_P3; b -= 512; }
    else if (b < 672) { src = p4; HW2 = 4096;  off = OFF_P4; b -= 640; }
    else              { src = p5; HW2 = 1024;  off = OFF_P5; b -= 672; }
    const int hw0 = b << 7;

    const int t   = threadIdx.x;
    const int hwq = t & 31;
    const int cg  = t >> 5;
    const int key = (hwq & 7) << 4;

    #pragma unroll
    for (int s = 0; s < 8; ++s) {
        const int c0 = (cg << 2) + (s << 5);
        const float* g = src + (size_t)c0 * HW2 + hw0 + (hwq << 2);
        const float4 a0 = *(const float4*)(g);
        const float4 a1 = *(const float4*)(g + HW2);
        const float4 a2 = *(const float4*)(g + 2 * (size_t)HW2);
        const float4 a3 = *(const float4*)(g + 3 * (size_t)HW2);
        const int cb = (c0 << 1) ^ key;
        unsigned char* base = &lds[(hwq << 2) * RB + cb];
        ushort4 w;
        w.x = f2bf(a0.x); w.y = f2bf(a1.x); w.z = f2bf(a2.x); w.w = f2bf(a3.x);
        *(ushort4*)(base) = w;
        w.x = f2bf(a0.y); w.y = f2bf(a1.y); w.z = f2bf(a2.y); w.w = f2bf(a3.y);
        *(ushort4*)(base + RB) = w;
        w.x = f2bf(a0.z); w.y = f2bf(a1.z); w.z = f2bf(a2.z); w.w = f2bf(a3.z);
        *(ushort4*)(base + 2 * RB) = w;
        w.x = f2bf(a0.w); w.y = f2bf(a1.w); w.z = f2bf(a2.w); w.w = f2bf(a3.w);
        *(ushort4*)(base + 3 * RB) = w;
    }
    __syncthreads();

    char* __restrict__ dstb = (char*)(ws + off + ((size_t)hw0 << 8));
    const int chunk = t & 31;
    const int hwl   = t >> 5;
    #pragma unroll
    for (int p = 0; p < 16; ++p) {
        const int hw = (p << 3) + hwl;
        const int k2 = ((hw >> 2) & 7) << 4;
        const uint4 v = *(const uint4*)&lds[hw * RB + ((chunk << 4) ^ k2)];
        *(uint4*)(dstb + hw * 512 + (chunk << 4)) = v;
    }
}

// ---------------- main ROI-align + 2x2 maxpool (64 channels per block) ----------------
// Staged path: window texel slices -> LINEAR LDS arena (no swizzle), gathers are
// ds_read_b64 at precomputed otab offsets + g8 (zero extra VALU per corner).
template <bool HWC>
__global__ __launch_bounds__(256, 3) void roi_align_k(
    const float* __restrict__ p2, const float* __restrict__ p3,
    const float* __restrict__ p4, const float* __restrict__ p5,
    const unsigned short* __restrict__ ws, const float* __restrict__ rois,
    const unsigned* __restrict__ perm, int N, float* __restrict__ out) {

    __shared__ float sxw0[PRE], sxw1[PRE], syw0[PRE], syw1[PRE];
    __shared__ int   sxc0[PRE], sxc1[PRE], syc0[PRE], syc1[PRE];
    __shared__ float4 wtab[PRE * PRE];              // 3136 B
    __shared__ int4   otab[PRE * PRE];              // 3136 B
    __shared__ unsigned short tlist[WTEX];          // 704 B
    __shared__ uint4 arena4[WTEX * 8];              // 45056 B: window slices OR sout (union)
    unsigned char* const arenaB = (unsigned char*)arena4;

    int n;
    if (HWC) {
        const int bid = blockIdx.x;
        int spos;
        if ((N & 7) == 0) spos = (bid & 7) * (N >> 3) + (bid >> 3);   // XCD-chunked
        else              spos = bid;
        n = (int)perm[spos];
    } else {
        n = blockIdx.x;
    }
    const int ch0 = blockIdx.y << 6;            // 0,64,128,192
    const float x1 = rois[n * 5 + 1];
    const float y1 = rois[n * 5 + 2];
    const float x2 = rois[n * 5 + 3];
    const float y2 = rois[n * 5 + 4];

    float w = x2 - x1; w = (w <= 0.f) ? 1e-14f : w;
    float h = y2 - y1; h = (h <= 0.f) ? 1e-14f : h;
    float kf = 4.f + log2f(sqrtf(w * h) * (1.f / 224.f));
    kf = fminf(fmaxf(kf, 2.f), 5.f);
    const float kr = rintf(kf);                 // round-half-even == jnp.round
    const int   lvl = (int)kr - 2;              // 0..3
    const float scale = exp2f(kr);
    const int   HW = 256 >> lvl;

    const int t = threadIdx.x;

    if (t < 2 * PRE) {
        const bool isx = t < PRE;
        const int  j = isx ? t : t - PRE;
        const float a1 = isx ? x1 : y1;
        const float a2 = isx ? x2 : y2;
        const float a1s = a1 / scale, a2s = a2 / scale;
        const float cen  = (a1s + a2s) * 0.5f;
        const float half = (a2s - a1s) * 0.5f;
        const float tt = -1.f + (2.f / 13.f) * (float)j;
        const float p  = cen + tt * half;
        const float p0 = floorf(p);
        const float d  = p - p0;
        const float HWf = (float)HW;
        const float m0 = (p0 >= 0.f && p0 < HWf) ? 1.f : 0.f;
        const float m1 = (p0 + 1.f >= 0.f && p0 + 1.f < HWf) ? 1.f : 0.f;
        const int c0i = min(max((int)p0, 0), HW - 1);
        const int c1i = min(max((int)p0 + 1, 0), HW - 1);
        if (isx) { sxw0[j] = (1.f - d) * m0; sxw1[j] = d * m1; sxc0[j] = c0i; sxc1[j] = c1i; }
        else     { syw0[j] = (1.f - d) * m0; syw1[j] = d * m1; syc0[j] = c0i; syc1[j] = c1i; }
    }
    __syncthreads();

    // window (sample coords are monotone in j/i)
    const int xs0 = sxc0[0], xs1 = sxc1[PRE - 1];
    const int ys0 = syc0[0], ys1 = syc1[PRE - 1];
    const int wx = xs1 - xs0 + 1;
    const int wy = ys1 - ys0 + 1;
    const int ntex = wx * wy;
    const bool staged = HWC && (ntex <= WTEX);

    if (HWC) {
        for (int s = t; s < PRE * PRE; s += 256) {
            const int i = s / PRE;
            const int j = s - i * PRE;
            wtab[s] = make_float4(syw0[i] * sxw0[j], syw0[i] * sxw1[j],
                                  syw1[i] * sxw0[j], syw1[i] * sxw1[j]);
            if (staged) {
                const int r0 = (syc0[i] - ys0) * wx - xs0;
                const int r1 = (syc1[i] - ys0) * wx - xs0;
                otab[s] = make_int4((r0 + sxc0[j]) << 7, (r0 + sxc1[j]) << 7,
                                    (r1 + sxc0[j]) << 7, (r1 + sxc1[j]) << 7);
            } else {
                otab[s] = make_int4((syc0[i] * HW + sxc0[j]) << 9, (syc0[i] * HW + sxc1[j]) << 9,
                                    (syc1[i] * HW + sxc0[j]) << 9, (syc1[i] * HW + sxc1[j]) << 9);
            }
        }
        if (staged) {
            for (int i = t; i < ntex; i += 256) {
                const int r = i / wx;
                const int c = i - r * wx;
                tlist[i] = (unsigned short)((ys0 + r) * HW + (xs0 + c));
            }
        }
        __syncthreads();
    }

    const int g   = t & 15;                     // ch-group (16 x 4ch = 64 ch)
    const int ph  = t >> 4;                     // 0..15 pixel phase
    const int g8  = g << 3;                     // lane byte offset within 128B slice

    float4 res0, res1, res2, res3;

    if (HWC) {
        const unsigned int off = (lvl == 0) ? OFF_P2 : (lvl == 1) ? OFF_P3 : (lvl == 2) ? OFF_P4 : OFF_P5;
        const char* __restrict__ gws = (const char*)(ws + off);

        if (staged) {
            // ---- parallel linear staging: texel tt's 128B ch-slice at arenaB[tt*128] ----
            const char* __restrict__ gsrc = gws + (ch0 << 1);
            const int nchunks = ntex << 3;      // 16B chunks
            for (int i = t; i < nchunks; i += 256) {
                const int tt  = i >> 3;
                const int sub = (i & 7) << 4;
                const int rc  = (int)tlist[tt];
                const uint4 v = *(const uint4*)(gsrc + ((size_t)rc << 9) + sub);
                *(uint4*)(arenaB + (tt << 7) + sub) = v;
            }
            __syncthreads();

            #define LD(o) (*(const uint2*)&arenaB[(o) + g8])
            #define DO_PIXEL(P, RES)                                                  \
            {                                                                         \
                const int p_ = (P);                                                   \
                const int oy_ = p_ / 7;                                               \
                const int ox_ = p_ - oy_ * 7;                                         \
                const int s00 = oy_ * 28 + (ox_ << 1);                                \
                const int4  oA = otab[s00];      const float4 wA = wtab[s00];         \
                const int4  oB = otab[s00 + 1];  const float4 wB = wtab[s00 + 1];     \
                const int4  oC = otab[s00 + 14]; const float4 wC = wtab[s00 + 14];    \
                const int4  oD = otab[s00 + 15]; const float4 wD = wtab[s00 + 15];    \
                const float4 vA = bilerp4(LD(oA.x), LD(oA.y), LD(oA.z), LD(oA.w), wA);\
                const float4 vB = bilerp4(LD(oB.x), LD(oB.y), LD(oB.z), LD(oB.w), wB);\
                const float4 vC = bilerp4(LD(oC.x), LD(oC.y), LD(oC.z), LD(oC.w), wC);\
                const float4 vD = bilerp4(LD(oD.x), LD(oD.y), LD(oD.z), LD(oD.w), wD);\
                RES.x = fmaxf(fmaxf(vA.x, vB.x), fmaxf(vC.x, vD.x));                  \
                RES.y = fmaxf(fmaxf(vA.y, vB.y), fmaxf(vC.y, vD.y));                  \
                RES.z = fmaxf(fmaxf(vA.z, vB.z), fmaxf(vC.z, vD.z));                  \
                RES.w = fmaxf(fmaxf(vA.w, vB.w), fmaxf(vC.w, vD.w));                  \
            }
            DO_PIXEL(ph, res0)
            DO_PIXEL(ph + 16, res1)
            DO_PIXEL(ph + 32, res2)
            if (ph == 0) DO_PIXEL(48, res3)
            #undef DO_PIXEL
            #undef LD
        } else {
            const int cb2 = (ch0 + (g << 2)) << 1;
            #define LD(o) (*(const uint2*)(gws + ((o) + cb2)))
            #define DO_PIXEL(P, RES)                                                  \
            {                                                                         \
                const int p_ = (P);                                                   \
                const int oy_ = p_ / 7;                                               \
                const int ox_ = p_ - oy_ * 7;                                         \
                const int s00 = oy_ * 28 + (ox_ << 1);                                \
                const int4  oA = otab[s00];      const float4 wA = wtab[s00];         \
                const int4  oB = otab[s00 + 1];  const float4 wB = wtab[s00 + 1];     \
                const int4  oC = otab[s00 + 14]; const float4 wC = wtab[s00 + 14];    \
                const int4  oD = otab[s00 + 15]; const float4 wD = wtab[s00 + 15];    \
                const uint2 A00 = LD(oA.x), A01 = LD(oA.y), A10 = LD(oA.z), A11 = LD(oA.w); \
                const uint2 B00 = LD(oB.x), B01 = LD(oB.y), B10 = LD(oB.z), B11 = LD(oB.w); \
                const uint2 C00 = LD(oC.x), C01 = LD(oC.y), C10 = LD(oC.z), C11 = LD(oC.w); \
                const uint2 D00 = LD(oD.x), D01 = LD(oD.y), D10 = LD(oD.z), D11 = LD(oD.w); \
                const float4 vA = bilerp4(A00, A01, A10, A11, wA);                    \
                const float4 vB = bilerp4(B00, B01, B10, B11, wB);                    \
                const float4 vC = bilerp4(C00, C01, C10, C11, wC);                    \
                const float4 vD = bilerp4(D00, D01, D10, D11, wD);                    \
                RES.x = fmaxf(fmaxf(vA.x, vB.x), fmaxf(vC.x, vD.x));                  \
                RES.y = fmaxf(fmaxf(vA.y, vB.y), fmaxf(vC.y, vD.y));                  \
                RES.z = fmaxf(fmaxf(vA.z, vB.z), fmaxf(vC.z, vD.z));                  \
                RES.w = fmaxf(fmaxf(vA.w, vB.w), fmaxf(vC.w, vD.w));                  \
            }
            DO_PIXEL(ph, res0)
            DO_PIXEL(ph + 16, res1)
            DO_PIXEL(ph + 32, res2)
            if (ph == 0) DO_PIXEL(48, res3)
            #undef DO_PIXEL
            #undef LD
        }
    } else {
        const int cbase = ch0 + (g << 2);
        const float* __restrict__ fbF = (lvl == 0) ? p2 : (lvl == 1) ? p3 : (lvl == 2) ? p4 : p5;
        const int HW2 = HW * HW;
        #define DO_PIXEL(P, RES)                                                      \
        {                                                                             \
            const int p_ = (P);                                                       \
            const int oy_ = p_ / 7;                                                   \
            const int ox_ = p_ - oy_ * 7;                                             \
            RES = make_float4(-3.4e38f, -3.4e38f, -3.4e38f, -3.4e38f);                \
            for (int sy = 0; sy < 2; ++sy) {                                          \
                const int i = oy_ * 2 + sy;                                           \
                const float wy0 = syw0[i], wy1 = syw1[i];                             \
                const int   yc0 = syc0[i], yc1 = syc1[i];                             \
                for (int sx = 0; sx < 2; ++sx) {                                      \
                    const int j = ox_ * 2 + sx;                                       \
                    const float w00 = wy0 * sxw0[j], w01 = wy0 * sxw1[j];             \
                    const float w10 = wy1 * sxw0[j], w11 = wy1 * sxw1[j];             \
                    const int   xc0 = sxc0[j], xc1 = sxc1[j];                         \
                    for (int k = 0; k < 4; ++k) {                                     \
                        const size_t cb = (size_t)(cbase + k) * HW2;                  \
                        const float a00 = fbF[cb + yc0 * HW + xc0];                   \
                        const float a01 = fbF[cb + yc0 * HW + xc1];                   \
                        const float a10 = fbF[cb + yc1 * HW + xc0];                   \
                        const float a11 = fbF[cb + yc1 * HW + xc1];                   \
                        const float vv = fmaf(a00, w00, fmaf(a01, w01, fmaf(a10, w10, a11 * w11))); \
                        if (k == 0) RES.x = fmaxf(RES.x, vv);                         \
                        else if (k == 1) RES.y = fmaxf(RES.y, vv);                    \
                        else if (k == 2) RES.z = fmaxf(RES.z, vv);                    \
                        else RES.w = fmaxf(RES.w, vv);                                \
                    }                                                                 \
                }                                                                     \
            }                                                                         \
        }
        DO_PIXEL(ph, res0)
        DO_PIXEL(ph + 16, res1)
        DO_PIXEL(ph + 32, res2)
        if (ph == 0) DO_PIXEL(48, res3)
        #undef DO_PIXEL
    }
    __syncthreads();   // window reads done -> arena becomes sout

    float* sout = (float*)arenaB;
    *(float4*)&sout[ph * SROW + (g << 2)] = res0;
    *(float4*)&sout[(ph + 16) * SROW + (g << 2)] = res1;
    *(float4*)&sout[(ph + 32) * SROW + (g << 2)] = res2;
    if (ph == 0) *(float4*)&sout[48 * SROW + (g << 2)] = res3;
    __syncthreads();

    // coalesced NCHW write of this 64-channel quarter
    const size_t ob = (size_t)n * OUT_PER_ROI + (size_t)ch0 * PIX;
    for (int o = t; o < QTR_OUT; o += 256) {
        const int c  = o / PIX;
        const int pp = o - c * PIX;
        out[ob + o] = sout[pp * SROW + c];
    }
}

extern "C" void kernel_launch(void* const* d_in, const int* in_sizes, int n_in,
                              void* d_out, int out_size, void* d_ws, size_t ws_size,
                              hipStream_t stream) {
    const float* p2   = (const float*)d_in[0];
    const float* p3   = (const float*)d_in[1];
    const float* p4   = (const float*)d_in[2];
    const float* p5   = (const float*)d_in[3];
    const float* rois = (const float*)d_in[4];
    float* out = (float*)d_out;
    const int N = in_sizes[4] / 5;

    const size_t need = (size_t)WS_ELEMS * sizeof(unsigned short) + 4096;
    if (ws_size >= need && N <= 1024) {
        unsigned short* ws = (unsigned short*)d_ws;
        unsigned* perm = (unsigned*)((char*)d_ws + (size_t)WS_ELEMS * sizeof(unsigned short));
        transpose_all_k<<<NTRANS + 1, 256, 0, stream>>>(p2, p3, p4, p5, ws, rois, perm, N);
        roi_align_k<true><<<dim3(N, 4), 256, 0, stream>>>(p2, p3, p4, p5, ws, rois, perm, N, out);
    } else {
        roi_align_k<false><<<dim3(N, 4), 256, 0, stream>>>(p2, p3, p4, p5, nullptr, rois, nullptr, N, out);
    }
}

// Round 17
// 48.780 us; speedup vs baseline: 1.5416x; 1.3590x over previous
//
#include <hip/hip_runtime.h>
#include <math.h>

#define C_CH 256
#define PRE 14
#define NPOOL 7
#define PIX (NPOOL * NPOOL)            // 49
#define OUT_PER_ROI (C_CH * PIX)       // 12544
#define HALF_OUT (128 * PIX)           // 6272
#define SROW 132                       // sout row stride: 128 ch + 4 pad (pixel-major)

// level offsets in bf16 elements inside HWC workspace
#define OFF_P2 0
#define OFF_P3 16777216u
#define OFF_P4 20971520u
#define OFF_P5 22020096u
#define WS_ELEMS 22282240u             // bf16 elements; perm array lives after this

#define RB 528                         // transpose LDS row stride in bytes (512 + 16)
#define NTRANS 680                     // transpose blocks (1..NTRANS); block 0 = sorter
#define NBKT 4096                      // sort buckets: lvl(2b) x yband(5b) x xband(5b)

static __device__ __forceinline__ unsigned short f2bf(float f) {
    unsigned int u = __float_as_uint(f);
    unsigned int r = (u + 0x7FFFu + ((u >> 16) & 1u)) >> 16;   // RNE
    return (unsigned short)r;
}
static __device__ __forceinline__ float bfLO(unsigned int u) { return __uint_as_float(u << 16); }
static __device__ __forceinline__ float bfHI(unsigned int u) { return __uint_as_float(u & 0xFFFF0000u); }

// 8-channel bilinear: 4 corner uint4 (8 bf16 ch each) + corner weights w -> lo/hi float4
static __device__ __forceinline__ void bilerp8(uint4 a00, uint4 a01, uint4 a10, uint4 a11,
                                               float4 w, float4& lo, float4& hi) {
    lo.x = fmaf(bfLO(a00.x), w.x, fmaf(bfLO(a01.x), w.y, fmaf(bfLO(a10.x), w.z, bfLO(a11.x) * w.w)));
    lo.y = fmaf(bfHI(a00.x), w.x, fmaf(bfHI(a01.x), w.y, fmaf(bfHI(a10.x), w.z, bfHI(a11.x) * w.w)));
    lo.z = fmaf(bfLO(a00.y), w.x, fmaf(bfLO(a01.y), w.y, fmaf(bfLO(a10.y), w.z, bfLO(a11.y) * w.w)));
    lo.w = fmaf(bfHI(a00.y), w.x, fmaf(bfHI(a01.y), w.y, fmaf(bfHI(a10.y), w.z, bfHI(a11.y) * w.w)));
    hi.x = fmaf(bfLO(a00.z), w.x, fmaf(bfLO(a01.z), w.y, fmaf(bfLO(a10.z), w.z, bfLO(a11.z) * w.w)));
    hi.y = fmaf(bfHI(a00.z), w.x, fmaf(bfHI(a01.z), w.y, fmaf(bfHI(a10.z), w.z, bfHI(a11.z) * w.w)));
    hi.z = fmaf(bfLO(a00.w), w.x, fmaf(bfLO(a01.w), w.y, fmaf(bfLO(a10.w), w.z, bfLO(a11.w) * w.w)));
    hi.w = fmaf(bfHI(a00.w), w.x, fmaf(bfHI(a01.w), w.y, fmaf(bfHI(a10.w), w.z, bfHI(a11.w) * w.w)));
}

// ---------------- fused transpose CHW fp32 -> HWC bf16 + ROI fine bucket sort ----------------
// Block 0: 4096-bucket counting sort of ROI indices by (level, y-band, x-band) -> perm,
//          overlapped with transpose. Blocks 1..680: R4-proven transpose.
__global__ __launch_bounds__(256) void transpose_all_k(
    const float* __restrict__ p2, const float* __restrict__ p3,
    const float* __restrict__ p4, const float* __restrict__ p5,
    unsigned short* __restrict__ ws, const float* __restrict__ rois,
    unsigned* __restrict__ perm, int N) {
    __shared__ unsigned char lds[128 * RB];    // 67584 B

    if (blockIdx.x == 0) {
        int* hist = (int*)lds;                                   // 16384 B
        int* tsum = (int*)(lds + NBKT * 4);                      // 1024 B
        unsigned short* kbuf = (unsigned short*)(lds + NBKT * 4 + 1024);  // 2048 B
        const int t = threadIdx.x;
        #pragma unroll
        for (int k = 0; k < NBKT / 256; ++k) hist[t + (k << 8)] = 0;
        __syncthreads();
        for (int i = t; i < N; i += 256) {
            const float x1 = rois[i * 5 + 1];
            const float y1 = rois[i * 5 + 2];
            const float x2 = rois[i * 5 + 3];
            const float y2 = rois[i * 5 + 4];
            float w = x2 - x1; w = (w <= 0.f) ? 1e-14f : w;
            float h = y2 - y1; h = (h <= 0.f) ? 1e-14f : h;
            float kf = 4.f + log2f(sqrtf(w * h) * (1.f / 224.f));
            kf = fminf(fmaxf(kf, 2.f), 5.f);
            const float kr = rintf(kf);
            const int lvl = (int)kr - 2;                 // 0..3
            const float inv = exp2f(-kr);
            const int yi = (int)(y1 * inv);
            const int xi = (int)(x1 * inv);
            const int sh = 3 - lvl;                      // 32 bands per level
            const int yb = (yi >> sh) & 31;
            const int xb = (xi >> sh) & 31;
            const int bkt = (lvl << 10) | (yb << 5) | xb;
            kbuf[i] = (unsigned short)bkt;
            atomicAdd(&hist[bkt], 1);
        }
        __syncthreads();
        {   // blocked exclusive prefix over 4096 bins (16 per thread)
            const int b0 = t << 4;
            int s = 0;
            #pragma unroll
            for (int k = 0; k < 16; ++k) s += hist[b0 + k];
            tsum[t] = s;
        }
        __syncthreads();
        if (t == 0) {
            int acc = 0;
            for (int k = 0; k < 256; ++k) { const int v = tsum[k]; tsum[k] = acc; acc += v; }
        }
        __syncthreads();
        {
            const int b0 = t << 4;
            int run = tsum[t];
            #pragma unroll
            for (int k = 0; k < 16; ++k) { const int v = hist[b0 + k]; hist[b0 + k] = run; run += v; }
        }
        __syncthreads();
        for (int i = t; i < N; i += 256) {
            const int pos = atomicAdd(&hist[kbuf[i]], 1);
            perm[pos] = (unsigned)i;
        }
        return;
    }

    int b = blockIdx.x - 1;
    const float* __restrict__ src;
    int HW2; unsigned int off;
    if (b < 512)      { src = p2; HW2 = 65536; off = OFF_P2; }
    else if (b < 640) { src = p3; HW2 = 16384; off = OFF_P3; b -= 512; }
    else if (b < 672) { src = p4; HW2 = 4096;  off = OFF_P4; b -= 640; }
    else              { src = p5; HW2 = 1024;  off = OFF_P5; b -= 672; }
    const int hw0 = b << 7;

    const int t   = threadIdx.x;
    const int hwq = t & 31;
    const int cg  = t >> 5;
    const int key = (hwq & 7) << 4;

    #pragma unroll
    for (int s = 0; s < 8; ++s) {
        const int c0 = (cg << 2) + (s << 5);
        const float* g = src + (size_t)c0 * HW2 + hw0 + (hwq << 2);
        const float4 a0 = *(const float4*)(g);
        const float4 a1 = *(const float4*)(g + HW2);
        const float4 a2 = *(const float4*)(g + 2 * (size_t)HW2);
        const float4 a3 = *(const float4*)(g + 3 * (size_t)HW2);
        const int cb = (c0 << 1) ^ key;
        unsigned char* base = &lds[(hwq << 2) * RB + cb];
        ushort4 w;
        w.x = f2bf(a0.x); w.y = f2bf(a1.x); w.z = f2bf(a2.x); w.w = f2bf(a3.x);
        *(ushort4*)(base) = w;
        w.x = f2bf(a0.y); w.y = f2bf(a1.y); w.z = f2bf(a2.y); w.w = f2bf(a3.y);
        *(ushort4*)(base + RB) = w;
        w.x = f2bf(a0.z); w.y = f2bf(a1.z); w.z = f2bf(a2.z); w.w = f2bf(a3.z);
        *(ushort4*)(base + 2 * RB) = w;
        w.x = f2bf(a0.w); w.y = f2bf(a1.w); w.z = f2bf(a2.w); w.w = f2bf(a3.w);
        *(ushort4*)(base + 3 * RB) = w;
    }
    __syncthreads();

    char* __restrict__ dstb = (char*)(ws + off + ((size_t)hw0 << 8));
    const int chunk = t & 31;
    const int hwl   = t >> 5;
    #pragma unroll
    for (int p = 0; p < 16; ++p) {
        const int hw = (p << 3) + hwl;
        const int k2 = ((hw >> 2) & 7) << 4;
        const uint4 v = *(const uint4*)&lds[hw * RB + ((chunk << 4) ^ k2)];
        *(uint4*)(dstb + hw * 512 + (chunk << 4)) = v;
    }
}

// ---------------- main ROI-align + 2x2 maxpool (128 channels per block) ----------------
// R11 uint4-gather body + fully-ordered perm + XCD-chunked mapping. (Best measured: R14)
template <bool HWC>
__global__ __launch_bounds__(256, 4) void roi_align_k(
    const float* __restrict__ p2, const float* __restrict__ p3,
    const float* __restrict__ p4, const float* __restrict__ p5,
    const unsigned short* __restrict__ ws, const float* __restrict__ rois,
    const unsigned* __restrict__ perm, int N, float* __restrict__ out) {

    __shared__ float sxw0[PRE], sxw1[PRE], syw0[PRE], syw1[PRE];
    __shared__ int   sxc0[PRE], sxc1[PRE], syc0[PRE], syc1[PRE];
    __shared__ float4 wtab[PRE * PRE];          // 3136 B
    __shared__ int4   otab[PRE * PRE];          // 3136 B
    __shared__ float  sout[PIX * SROW];         // 25872 B (pixel-major)

    int n;
    if (HWC) {
        const int bid = blockIdx.x;
        int spos;
        if ((N & 7) == 0) spos = (bid & 7) * (N >> 3) + (bid >> 3);   // XCD-chunked
        else              spos = bid;
        n = (int)perm[spos];
    } else {
        n = blockIdx.x;
    }
    const int ch0 = blockIdx.y << 7;            // 0 or 128
    const float x1 = rois[n * 5 + 1];
    const float y1 = rois[n * 5 + 2];
    const float x2 = rois[n * 5 + 3];
    const float y2 = rois[n * 5 + 4];

    float w = x2 - x1; w = (w <= 0.f) ? 1e-14f : w;
    float h = y2 - y1; h = (h <= 0.f) ? 1e-14f : h;
    float kf = 4.f + log2f(sqrtf(w * h) * (1.f / 224.f));
    kf = fminf(fmaxf(kf, 2.f), 5.f);
    const float kr = rintf(kf);                 // round-half-even == jnp.round
    const int   lvl = (int)kr - 2;              // 0..3
    const float scale = exp2f(kr);
    const int   HW = 256 >> lvl;

    const int t = threadIdx.x;

    if (t < 2 * PRE) {
        const bool isx = t < PRE;
        const int  j = isx ? t : t - PRE;
        const float a1 = isx ? x1 : y1;
        const float a2 = isx ? x2 : y2;
        const float a1s = a1 / scale, a2s = a2 / scale;
        const float cen  = (a1s + a2s) * 0.5f;
        const float half = (a2s - a1s) * 0.5f;
        const float tt = -1.f + (2.f / 13.f) * (float)j;
        const float p  = cen + tt * half;
        const float p0 = floorf(p);
        const float d  = p - p0;
        const float HWf = (float)HW;
        const float m0 = (p0 >= 0.f && p0 < HWf) ? 1.f : 0.f;
        const float m1 = (p0 + 1.f >= 0.f && p0 + 1.f < HWf) ? 1.f : 0.f;
        const int c0i = min(max((int)p0, 0), HW - 1);
        const int c1i = min(max((int)p0 + 1, 0), HW - 1);
        if (isx) { sxw0[j] = (1.f - d) * m0; sxw1[j] = d * m1; sxc0[j] = c0i; sxc1[j] = c1i; }
        else     { syw0[j] = (1.f - d) * m0; syw1[j] = d * m1; syc0[j] = c0i; syc1[j] = c1i; }
    }
    __syncthreads();

    if (HWC) {
        for (int s = t; s < PRE * PRE; s += 256) {
            const int i = s / PRE;
            const int j = s - i * PRE;
            wtab[s] = make_float4(syw0[i] * sxw0[j], syw0[i] * sxw1[j],
                                  syw1[i] * sxw0[j], syw1[i] * sxw1[j]);
            otab[s] = make_int4((syc0[i] * HW + sxc0[j]) << 9, (syc0[i] * HW + sxc1[j]) << 9,
                                (syc1[i] * HW + sxc0[j]) << 9, (syc1[i] * HW + sxc1[j]) << 9);
        }
        __syncthreads();
    }

    if (HWC) {
        const int g   = t & 15;                 // ch-group: 16 x 8ch = 128 ch
        const int ph  = t >> 4;                 // 0..15 pixel phase
        const unsigned int off = (lvl == 0) ? OFF_P2 : (lvl == 1) ? OFF_P3 : (lvl == 2) ? OFF_P4 : OFF_P5;
        const char* __restrict__ base = (const char*)(ws + off);
        const int cb2 = (ch0 + (g << 3)) << 1;

        #define DO_PIXEL(P)                                                           \
        {                                                                             \
            const int p_ = (P);                                                       \
            const int oy_ = p_ / 7;                                                   \
            const int ox_ = p_ - oy_ * 7;                                             \
            const int s00 = oy_ * 28 + (ox_ << 1);                                    \
            const int4  oA = otab[s00];      const float4 wA = wtab[s00];             \
            const int4  oB = otab[s00 + 1];  const float4 wB = wtab[s00 + 1];         \
            const int4  oC = otab[s00 + 14]; const float4 wC = wtab[s00 + 14];        \
            const int4  oD = otab[s00 + 15]; const float4 wD = wtab[s00 + 15];        \
            const uint4 A00 = *(const uint4*)(base + (oA.x + cb2));                   \
            const uint4 A01 = *(const uint4*)(base + (oA.y + cb2));                   \
            const uint4 A10 = *(const uint4*)(base + (oA.z + cb2));                   \
            const uint4 A11 = *(const uint4*)(base + (oA.w + cb2));                   \
            const uint4 B00 = *(const uint4*)(base + (oB.x + cb2));                   \
            const uint4 B01 = *(const uint4*)(base + (oB.y + cb2));                   \
            const uint4 B10 = *(const uint4*)(base + (oB.z + cb2));                   \
            const uint4 B11 = *(const uint4*)(base + (oB.w + cb2));                   \
            const uint4 C00 = *(const uint4*)(base + (oC.x + cb2));                   \
            const uint4 C01 = *(const uint4*)(base + (oC.y + cb2));                   \
            const uint4 C10 = *(const uint4*)(base + (oC.z + cb2));                   \
            const uint4 C11 = *(const uint4*)(base + (oC.w + cb2));                   \
            const uint4 D00 = *(const uint4*)(base + (oD.x + cb2));                   \
            const uint4 D01 = *(const uint4*)(base + (oD.y + cb2));                   \
            const uint4 D10 = *(const uint4*)(base + (oD.z + cb2));                   \
            const uint4 D11 = *(const uint4*)(base + (oD.w + cb2));                   \
            float4 aLo, aHi, bLo, bHi, cLo, cHi, dLo, dHi;                            \
            bilerp8(A00, A01, A10, A11, wA, aLo, aHi);                                \
            bilerp8(B00, B01, B10, B11, wB, bLo, bHi);                                \
            bilerp8(C00, C01, C10, C11, wC, cLo, cHi);                                \
            bilerp8(D00, D01, D10, D11, wD, dLo, dHi);                                \
            float4 mLo, mHi;                                                          \
            mLo.x = fmaxf(fmaxf(aLo.x, bLo.x), fmaxf(cLo.x, dLo.x));                  \
            mLo.y = fmaxf(fmaxf(aLo.y, bLo.y), fmaxf(cLo.y, dLo.y));                  \
            mLo.z = fmaxf(fmaxf(aLo.z, bLo.z), fmaxf(cLo.z, dLo.z));                  \
            mLo.w = fmaxf(fmaxf(aLo.w, bLo.w), fmaxf(cLo.w, dLo.w));                  \
            mHi.x = fmaxf(fmaxf(aHi.x, bHi.x), fmaxf(cHi.x, dHi.x));                  \
            mHi.y = fmaxf(fmaxf(aHi.y, bHi.y), fmaxf(cHi.y, dHi.y));                  \
            mHi.z = fmaxf(fmaxf(aHi.z, bHi.z), fmaxf(cHi.z, dHi.z));                  \
            mHi.w = fmaxf(fmaxf(aHi.w, bHi.w), fmaxf(cHi.w, dHi.w));                  \
            *(float4*)&sout[p_ * SROW + (g << 3)] = mLo;                              \
            *(float4*)&sout[p_ * SROW + (g << 3) + 4] = mHi;                          \
        }

        DO_PIXEL(ph)
        DO_PIXEL(ph + 16)
        DO_PIXEL(ph + 32)
        if (ph == 0) DO_PIXEL(48)
        #undef DO_PIXEL
    } else {
        const int g     = t & 31;
        const int s     = t >> 5;
        const int cbase = ch0 + (g << 2);
        const float* __restrict__ fbF = (lvl == 0) ? p2 : (lvl == 1) ? p3 : (lvl == 2) ? p4 : p5;
        const int HW2 = HW * HW;
        for (int p = s; p < PIX; p += 8) {
            const int oy = p / 7;
            const int ox = p - oy * 7;
            float4 m = make_float4(-3.4e38f, -3.4e38f, -3.4e38f, -3.4e38f);
            #pragma unroll
            for (int sy = 0; sy < 2; ++sy) {
                const int i = oy * 2 + sy;
                const float wy0 = syw0[i], wy1 = syw1[i];
                const int   yc0 = syc0[i], yc1 = syc1[i];
                #pragma unroll
                for (int sx = 0; sx < 2; ++sx) {
                    const int j = ox * 2 + sx;
                    const float w00 = wy0 * sxw0[j], w01 = wy0 * sxw1[j];
                    const float w10 = wy1 * sxw0[j], w11 = wy1 * sxw1[j];
                    const int   xc0 = sxc0[j], xc1 = sxc1[j];
                    float vv[4];
                    #pragma unroll
                    for (int k = 0; k < 4; ++k) {
                        const size_t cb = (size_t)(cbase + k) * HW2;
                        const float a00 = fbF[cb + yc0 * HW + xc0];
                        const float a01 = fbF[cb + yc0 * HW + xc1];
                        const float a10 = fbF[cb + yc1 * HW + xc0];
                        const float a11 = fbF[cb + yc1 * HW + xc1];
                        vv[k] = fmaf(a00, w00, fmaf(a01, w01, fmaf(a10, w10, a11 * w11)));
                    }
                    m.x = fmaxf(m.x, vv[0]);
                    m.y = fmaxf(m.y, vv[1]);
                    m.z = fmaxf(m.z, vv[2]);
                    m.w = fmaxf(m.w, vv[3]);
                }
            }
            *(float4*)&sout[p * SROW + (g << 2)] = m;
        }
    }
    __syncthreads();

    // coalesced NCHW write of this channel-half
    const size_t ob = (size_t)n * OUT_PER_ROI + (size_t)ch0 * PIX;
    for (int o = t; o < HALF_OUT; o += 256) {
        const int c  = o / PIX;
        const int pp = o - c * PIX;
        out[ob + o] = sout[pp * SROW + c];
    }
}

extern "C" void kernel_launch(void* const* d_in, const int* in_sizes, int n_in,
                              void* d_out, int out_size, void* d_ws, size_t ws_size,
                              hipStream_t stream) {
    const float* p2   = (const float*)d_in[0];
    const float* p3   = (const float*)d_in[1];
    const float* p4   = (const float*)d_in[2];
    const float* p5   = (const float*)d_in[3];
    const float* rois = (const float*)d_in[4];
    float* out = (float*)d_out;
    const int N = in_sizes[4] / 5;

    const size_t need = (size_t)WS_ELEMS * sizeof(unsigned short) + 4096;
    if (ws_size >= need && N <= 1024) {
        unsigned short* ws = (unsigned short*)d_ws;
        unsigned* perm = (unsigned*)((char*)d_ws + (size_t)WS_ELEMS * sizeof(unsigned short));
        transpose_all_k<<<NTRANS + 1, 256, 0, stream>>>(p2, p3, p4, p5, ws, rois, perm, N);
        roi_align_k<true><<<dim3(N, 2), 256, 0, stream>>>(p2, p3, p4, p5, ws, rois, perm, N, out);
    } else {
        roi_align_k<false><<<dim3(N, 2), 256, 0, stream>>>(p2, p3, p4, p5, nullptr, rois, nullptr, N, out);
    }
}